// Round 14
// baseline (7495.359 us; speedup 1.0000x reference)
//
#include <hip/hip_runtime.h>
#include <stdint.h>

typedef uint32_t u32; typedef uint16_t u16; typedef unsigned long long u64;
typedef __attribute__((ext_vector_type(8))) short short8;
typedef __attribute__((ext_vector_type(4))) float f32x4;

#define DEV static __device__ __forceinline__
#define MFMA16 __builtin_amdgcn_mfma_f32_16x16x32_bf16

#define BATCH 512
#define CD    64
#define ZL    16
#define HID   512
#define H2D   256
#define NC    9
#define SLEN  64
#define L1    35

#define JAX_PARTITIONABLE 1

// ---- workspace layout (f32-word offsets) ----
#define P_W      2850816   /* u16 per W limb plane-set */
#define WOFF_SKH 4276224   /* skel_hi u16 [64][512][16] */
#define WOFF_HPL 4538368   /* 4 states x 3 limbs x 262144 u16 */
#define WOFF_HF  6111232   /* h1_0 f32 262144 (state0 init) */
#define WOFF_LOG 7159808   /* f32 [64][512][16] */
#define WOFF_FLG 7684096   /* u32 flgH[256] + flgL[256] */
#define WOFF_XH  9175040   /* xin limb planes: 2 x 8,388,608 u16 */

template<int V> struct IC { static constexpr int value = V; };

DEV float bf2f(u16 h){ u32 u = ((u32)h) << 16; float f; __builtin_memcpy(&f,&u,4); return f; }
DEV u16 f2bf(float f){ u32 u; __builtin_memcpy(&u,&f,4); return (u16)((u + 0x7FFFu + ((u>>16)&1u)) >> 16); }

DEV float ldf(const float* p){ return __hip_atomic_load(p, __ATOMIC_RELAXED, __HIP_MEMORY_SCOPE_AGENT); }
DEV u32 ldu32(const u32* p){ return __hip_atomic_load(p, __ATOMIC_RELAXED, __HIP_MEMORY_SCOPE_AGENT); }
DEV u64 ldu64(const u64* p){ return __hip_atomic_load(p, __ATOMIC_RELAXED, __HIP_MEMORY_SCOPE_AGENT); }
DEV void stu32(u32* p, u32 v){ __hip_atomic_store(p, v, __ATOMIC_RELAXED, __HIP_MEMORY_SCOPE_AGENT); }

// ---------------- Threefry-2x32 ----------------
DEV void threefry2x32(u32 k0, u32 k1, u32 x0, u32 x1, u32 &o0, u32 &o1){
  const u32 ks2 = k0 ^ k1 ^ 0x1BD11BDAu;
#define TF_R(d) { x0 += x1; x1 = (x1 << (d)) | (x1 >> (32 - (d))); x1 ^= x0; }
  x0 += k0; x1 += k1;
  TF_R(13) TF_R(15) TF_R(26) TF_R(6)
  x0 += k1;  x1 += ks2 + 1u;
  TF_R(17) TF_R(29) TF_R(16) TF_R(24)
  x0 += ks2; x1 += k0 + 2u;
  TF_R(13) TF_R(15) TF_R(26) TF_R(6)
  x0 += k0;  x1 += k1 + 3u;
  TF_R(17) TF_R(29) TF_R(16) TF_R(24)
  x0 += k1;  x1 += ks2 + 4u;
  TF_R(13) TF_R(15) TF_R(26) TF_R(6)
  x0 += ks2; x1 += k0 + 5u;
#undef TF_R
  o0 = x0; o1 = x1;
}
DEV void step_key(int t, u32 &ka, u32 &kb){
#if JAX_PARTITIONABLE
  threefry2x32(0u, 42u, 0u, (u32)t, ka, kb);
#else
  u32 j0 = 2u*(u32)t, j1 = j0 + 1u, a0, a1;
  if (j0 < 64u){ threefry2x32(0u,42u, j0, 64u+j0, a0, a1); ka = a0; }
  else         { threefry2x32(0u,42u, j0-64u, j0, a0, a1); ka = a1; }
  if (j1 < 64u){ threefry2x32(0u,42u, j1, 64u+j1, a0, a1); kb = a0; }
  else         { threefry2x32(0u,42u, j1-64u, j1, a0, a1); kb = a1; }
#endif
}
DEV float rng_uniform(u32 ka, u32 kb, u32 f){
  u32 bits, o0, o1;
#if JAX_PARTITIONABLE
  threefry2x32(ka, kb, 0u, f, o0, o1);
  bits = o0 ^ o1;
#else
  const u32 HALF = (u32)(BATCH*NC/2);
  if (f < HALF){ threefry2x32(ka, kb, f, f+HALF, o0, o1); bits = o0; }
  else         { threefry2x32(ka, kb, f-HALF, f, o0, o1); bits = o1; }
#endif
  u32 fb = (bits >> 9) | 0x3F800000u;
  float fv; __builtin_memcpy(&fv,&fb,4);
  return fv - 1.0f;
}

// ---------------- ConvT1 ----------------
__global__ __launch_bounds__(256) void k_conv1(
    const float* __restrict__ z, const float* __restrict__ w1, const float* __restrict__ b1,
    const float* __restrict__ g1, const float* __restrict__ bt1, const float* __restrict__ m1,
    const float* __restrict__ v1, float* __restrict__ y1out)
{
  int t = blockIdx.x, bg = blockIdx.y*8, tid = threadIdx.x;
  __shared__ float zsh[2][8][CD];
  int k0 = t & 1, sA = (t-k0)>>1, sB = sA-1;
  bool vA = (sA>=0 && sA<ZL), vB = (sB>=0 && sB<ZL);
  for (int l = tid; l < 2*8*CD; l += 256){
    int p = l>>9, bb = (l>>6)&7, i = l&63;
    int s = p ? sB : sA; bool v = p ? vB : vA;
    zsh[p][bb][i] = v ? z[((bg+bb)*CD+i)*ZL + s] : 0.f;
  }
  __syncthreads();
  const float4* w1v = (const float4*)w1;
  for (int o = tid; o < HID; o += 256){
    float acc[8] = {0,0,0,0,0,0,0,0};
    for (int i = 0; i < CD; i++){
      float4 wv = w1v[i*HID + o];
      float wA = k0 ? wv.y : wv.x, wB = k0 ? wv.w : wv.z;
      #pragma unroll
      for (int bb = 0; bb < 8; bb++) acc[bb] += zsh[0][bb][i]*wA + zsh[1][bb][i]*wB;
    }
    float xb = b1[o], sc = g1[o]/sqrtf(v1[o]+1e-5f), mm = m1[o], be = bt1[o];
    #pragma unroll
    for (int bb = 0; bb < 8; bb++){
      float y = (acc[bb]+xb-mm)*sc + be;
      y = (y>0.f)? y : 0.2f*y;
      y1out[((bg+bb)*L1 + t)*HID + o] = y;
    }
  }
}

// ---------------- ConvT2 -> xin 2 limb planes [t][b][256] ----------------
__global__ __launch_bounds__(256) void k_conv2(
    const float* __restrict__ y1, const float* __restrict__ w2, const float* __restrict__ b2,
    const float* __restrict__ g2, const float* __restrict__ bt2, const float* __restrict__ m2,
    const float* __restrict__ v2, u16* __restrict__ xh, u16* __restrict__ xl)
{
  int t = blockIdx.x, bg = blockIdx.y*8, tid = threadIdx.x;
  __shared__ float ysh[2][8][HID];
  int k0 = t & 1, sA = (t-k0)>>1, sB = sA-1;
  bool vB = (sB >= 0);
  for (int l = tid; l < 2*8*HID; l += 256){
    int p = l>>12, bb = (l>>9)&7, o = l&511;
    int s = p ? sB : sA; bool v = p ? vB : true;
    ysh[p][bb][o] = v ? y1[((bg+bb)*L1 + s)*HID + o] : 0.f;
  }
  __syncthreads();
  int c = tid;
  float acc[8] = {0,0,0,0,0,0,0,0};
  const float4* w2v = (const float4*)w2;
  for (int o4 = 0; o4 < HID; o4 += 4){
    float wA[4], wB[4];
    #pragma unroll
    for (int j = 0; j < 4; j++){
      float4 wv = w2v[(o4+j)*H2D + c];
      wA[j] = k0 ? wv.y : wv.x; wB[j] = k0 ? wv.w : wv.z;
    }
    #pragma unroll
    for (int bb = 0; bb < 8; bb++){
      const float4 ya = *(const float4*)&ysh[0][bb][o4];
      const float4 yb = *(const float4*)&ysh[1][bb][o4];
      acc[bb] += ya.x*wA[0]+ya.y*wA[1]+ya.z*wA[2]+ya.w*wA[3]
               + yb.x*wB[0]+yb.y*wB[1]+yb.z*wB[2]+yb.w*wB[3];
    }
  }
  float xb = b2[c], sc = g2[c]/sqrtf(v2[c]+1e-5f), mm = m2[c], be = bt2[c];
  #pragma unroll
  for (int bb = 0; bb < 8; bb++){
    float y = (acc[bb]+xb-mm)*sc + be;
    y = (y>0.f)? y : 0.2f*y;
    u16 hi = f2bf(y); u16 lo = f2bf(y - bf2f(hi));
    size_t o = ((size_t)t*512 + bg + bb)*256 + c;
    xh[o] = hi; xl[o] = lo;
  }
}

// ---------------- prep: W 3-limb k-major planes, skel_hi, zero logacc+flags ------
// cat K-layout PERMUTED to [xin 256 | skel 9 | out 9 | pad] (wih1 cols permuted).
__global__ __launch_bounds__(256) void k_prep(
    const float* __restrict__ wih1, const float* __restrict__ whh1,
    const float* __restrict__ wih2, const float* __restrict__ whh2,
    const float* __restrict__ skel, float* __restrict__ ws)
{
  u16* wp = (u16*)ws;
  u16* skh = (u16*)(ws + WOFF_SKH);
  float* logacc = ws + WOFF_LOG;
  u32* flg = (u32*)(ws + WOFF_FLG);
  int stride = gridDim.x*256, i0 = blockIdx.x*256 + threadIdx.x;
  for (int i = i0; i < P_W; i += stride){
    int r = i; float v;
    if (r < 491520){
      int n = r/320, k = r - n*320; v = 0.f;
      if (k < 256)      v = wih1[(size_t)n*274 + 9 + k];          // xin
      else if (k < 265) v = wih1[(size_t)n*274 + 265 + (k-256)];  // skel
      else if (k < 274) v = wih1[(size_t)n*274 + (k-265)];        // out
    }
    else if (r < 1277952){ int rr = r-491520;  int n = rr>>9, k = rr&511; v = whh1[((size_t)n<<9)+k]; }
    else if (r < 2064384){ int rr = r-1277952; int n = rr>>9, k = rr&511; v = wih2[((size_t)n<<9)+k]; }
    else                 { int rr = r-2064384; int n = rr>>9, k = rr&511; v = whh2[((size_t)n<<9)+k]; }
    u16 l0 = f2bf(v);
    float r1 = v - bf2f(l0); u16 l1 = f2bf(r1);
    float r2 = r1 - bf2f(l1); u16 l2 = f2bf(r2);
    wp[i] = l0; wp[P_W + i] = l1; wp[2*P_W + i] = l2;
  }
  for (int i = i0; i < 524288; i += stride){
    int c = i & 15, r = i >> 4, b = r & 511, tt = r >> 9;
    float v = (c < 9) ? skel[((size_t)b*64 + tt)*9 + c] : 0.f;
    skh[i] = f2bf(v);
  }
  for (int i = i0; i < 524288; i += stride) logacc[i] = 0.f;
  for (int i = i0; i < 512; i += stride) flg[i] = 0u;
}

// ---------------- h0: h1a f32 + 3 limb planes (state 0) ----------------
__global__ __launch_bounds__(256) void k_h0(
    const float* __restrict__ se, const float* __restrict__ w, const float* __restrict__ bias,
    float* __restrict__ ws)
{
  float* h1af = ws + WOFF_HF;
  u16* hpl = (u16*)(ws + WOFF_HPL);
  int b = blockIdx.x, tid = threadIdx.x;
  __shared__ float ssh[HID];
  for (int i = tid; i < HID; i += 256) ssh[i] = se[b*HID + i];
  __syncthreads();
  for (int j = tid; j < HID; j += 256){
    float acc = 0.f;
    for (int q = 0; q < HID; q++) acc += ssh[q]*w[j*HID + q];
    float v = acc + bias[j];
    h1af[(size_t)b*512 + j] = v;
    u16 l0 = f2bf(v);
    float r1 = v - bf2f(l0); u16 l1 = f2bf(r1);
    float r2 = r1 - bf2f(l1); u16 l2 = f2bf(r2);
    hpl[(size_t)b*512 + j] = l0;
    hpl[262144 + (size_t)b*512 + j] = l1;
    hpl[524288 + (size_t)b*512 + j] = l2;
  }
}

// ---------------- persistent MFMA recurrence (3-limb bf16 split-6) ----------------
// r11 structure + W DIRECT global->reg (Wbuf LDS round-trip deleted).
// W is L2-resident via the XCD decode (r11-proven, FETCH 1.78GB), so the
// per-wave fragment gather hits L2 (~200cyc) with 2 barriers of slack.
// Identical W bits reach identical MFMAs in identical order -> numerics-free.
// 768 thr = 12 waves = (gate g, m-half mh, n-half jn); 16x16x32 MFMA;
// A reg-staged ->LDS (pitch 72) depth-2; W in 2 register banks (6 short8 each).
// soft_bar waits lgkmcnt ONLY; LDS 49.5 KB.
__global__ __launch_bounds__(768, 1) void k_persist(
    float* __restrict__ ws,
    const float* __restrict__ bih1, const float* __restrict__ bhh1,
    const float* __restrict__ bih2, const float* __restrict__ bhh2,
    const float* __restrict__ nfw,  const float* __restrict__ nfb,
    float* __restrict__ dout)
{
  const int tid = threadIdx.x;
  const int wvid = __builtin_amdgcn_readfirstlane(tid >> 6);
  const int g  = wvid >> 2;           // gate 0..2
  const int mh = (wvid >> 1) & 1;     // m-half
  const int jn = wvid & 1;            // n-half
  const int lane = tid & 63;
  const int mloc = lane & 15;
  const int q8 = (lane >> 4) * 8;
  const int q4 = (lane >> 4) * 4;
  // XCD-aware decode (bijective): xcd = bid&7 -> nstrips {2*xcd, 2*xcd+1}
  const int bid = blockIdx.x;
  const int xcd = bid & 7;
  const int rr2 = bid >> 3;                    // 0..31
  const int bg = rr2 >> 1;                     // 0..15
  const int nstrip = (xcd << 1) | (rr2 & 1);   // 0..15
  const int b0 = bg * 32;
  const int n0 = nstrip * 32;

  u16* wp = (u16*)ws;
  const u16* skh = (const u16*)(ws + WOFF_SKH);
  u16* hpl = (u16*)(ws + WOFF_HPL);
  const float* h1af = ws + WOFF_HF;
  float* logacc = ws + WOFF_LOG;
  u32* flgH = (u32*)(ws + WOFF_FLG);
  u32* flgL = flgH + 256;
  const u16* xh = (const u16*)(ws + WOFF_XH);
  const u16* xl = xh + 8388608;

  __shared__ __align__(16) u16 Abuf[2][3][32][72];     // 27,648 B
  __shared__ __align__(16) float eg[4][32][33];        // 16,896 B
  __shared__ __align__(16) float h2loc[32][33];        //  4,224 B
  __shared__ __align__(16) u16 out_sh[32][12];         //    768 B

  int t = 0;
  float2 hp1 = {0.f,0.f}, hp2 = {0.f,0.f};

  // prologue: zero out_sh, load own h1_0 tile into regs (tid<512)
  if (tid < 384) ((u16*)out_sh)[tid] = 0;
  if (tid < 512){
    int bi = tid >> 4, nl2 = (tid & 15)*2;
    hp1.x = h1af[(size_t)(b0+bi)*512 + n0 + nl2];
    hp1.y = h1af[(size_t)(b0+bi)*512 + n0 + nl2 + 1];
  }

  auto soft_bar = [&](){
    __builtin_amdgcn_sched_barrier(0);
    asm volatile("s_waitcnt lgkmcnt(0)" ::: "memory");
    __builtin_amdgcn_s_barrier();
    __builtin_amdgcn_sched_barrier(0);
  };
  auto arrive = [&](u32* f, u32 tok){
    __syncthreads();
    if (tid == 0) __hip_atomic_store(&f[bg*16 + nstrip], tok, __ATOMIC_RELEASE, __HIP_MEMORY_SCOPE_AGENT);
  };
  auto waitbar = [&](u32* f, u32 tok){
    if (tid < 16) while (ldu32(&f[bg*16 + tid]) < tok) __builtin_amdgcn_s_sleep(2);
    __syncthreads();
  };

  // ---- one GRU mat-pair phase: acc += A(K) * W^T strip, K in 64-wide windows ----
  auto run_phase = [&](auto mc, auto nwc, int Kp, size_t SUB, const u16* hb, f32x4 &acc){
    constexpr int MODE = decltype(mc)::value;   // 0 = cat (2 A-limbs), 1 = h-state (3)
    constexpr int NW = decltype(nwc)::value;
    short8 RWA[6], RWB[6];
    u64 RaA[2], RaB[2];

    const u16* wbase = wp + SUB + (size_t)(g*512 + n0 + jn*16 + mloc)*(size_t)Kp + q8;

    auto loadW = [&](short8 (&R)[6], int kc){
      #pragma unroll
      for (int limb = 0; limb < 3; limb++)
        #pragma unroll
        for (int ks = 0; ks < 2; ks++)
          R[limb*2 + ks] = *(const short8*)(wbase + (size_t)limb*P_W + kc + ks*32);
    };
    auto loadA = [&](u64 (&R)[2], int kc){
      int idx = tid;
      if constexpr (MODE == 1){
        int p = idx >> 8, r = idx & 255, bi = r >> 3, ck = r & 7;
        const u16* src = hb + (size_t)p*262144 + (size_t)(b0+bi)*512 + kc + ck*8;
        R[0] = ldu64((const u64*)src);
        R[1] = ldu64((const u64*)(src + 4));
      } else {
        if (idx < 512){
          int p = idx >> 8, r = idx & 255, bi = r >> 3, ck = r & 7;
          if (kc < 256){
            const u64* src = (const u64*)((p ? xl : xh) + ((size_t)t*512 + b0 + bi)*256 + kc + ck*8);
            R[0] = src[0]; R[1] = src[1];
          } else {
            u64 w0 = 0, w1 = 0;
            if (p == 0){
              #pragma unroll
              for (int e2 = 0; e2 < 4; e2++){
                int kg = 256 + ck*8 + e2;
                u16 val = 0;
                if (kg < 265) val = skh[((size_t)t*512 + b0 + bi)*16 + (kg - 256)];
                else if (kg < 274) val = out_sh[bi][kg - 265];
                w0 |= ((u64)val) << (16*e2);
              }
              #pragma unroll
              for (int e2 = 0; e2 < 4; e2++){
                int kg = 260 + ck*8 + e2;
                u16 val = 0;
                if (kg < 265) val = skh[((size_t)t*512 + b0 + bi)*16 + (kg - 256)];
                else if (kg < 274) val = out_sh[bi][kg - 265];
                w1 |= ((u64)val) << (16*e2);
              }
            }
            R[0] = w0; R[1] = w1;
          }
        }
      }
    };
    auto writeA = [&](int buf, u64 (&R)[2]){
      constexpr int NCH = (MODE == 1) ? 768 : 512;
      int idx = tid;
      if (idx < NCH){
        int p = idx >> 8, r = idx & 255, bi = r >> 3, ck = r & 7;
        u64* d = (u64*)&Abuf[buf][p][bi][ck*8];
        d[0] = R[0]; d[1] = R[1];
      }
    };
    auto compute = [&](int buf, short8 (&RW)[6]){
      const int ar = mh*16 + mloc;
      #pragma unroll
      for (int ks = 0; ks < 2; ks++){
        const int ko = ks*32 + q8;
        short8 a0 = *(const short8*)&Abuf[buf][0][ar][ko];
        short8 a1 = *(const short8*)&Abuf[buf][1][ar][ko];
        short8 a2 = {};
        if constexpr (MODE == 1) a2 = *(const short8*)&Abuf[buf][2][ar][ko];
        short8 w0 = RW[0*2 + ks];
        short8 w1 = RW[1*2 + ks];
        short8 w2 = RW[2*2 + ks];
        acc = MFMA16(a0, w0, acc, 0, 0, 0);
        acc = MFMA16(a0, w1, acc, 0, 0, 0);
        acc = MFMA16(a1, w0, acc, 0, 0, 0);
        acc = MFMA16(a0, w2, acc, 0, 0, 0);
        if constexpr (MODE == 1) acc = MFMA16(a2, w0, acc, 0, 0, 0);
        acc = MFMA16(a1, w1, acc, 0, 0, 0);
      }
    };

    // prologue: W/A for windows 0,1 issued; A(0) written to LDS
    loadW(RWA, 0); loadA(RaA, 0);
    loadW(RWB, 64); loadA(RaB, 64);
    writeA(0, RaA);
    soft_bar();

    // stepw(w): A-prefetch w+2; compute w (W from regs, loaded 2 windows back);
    // refill freed W bank; write A(w+1); barrier (lgkm only).
    auto stepw = [&](int w, short8 (&RWc)[6], u64 (&Al)[2], u64 (&As)[2]){
      if (w + 2 < NW) loadA(Al, (w+2)*64);
      compute(w & 1, RWc);
      if (w + 2 < NW) loadW(RWc, (w+2)*64);
      if (w + 1 < NW) writeA((w+1)&1, As);
      soft_bar();
    };
    #pragma unroll
    for (int w = 0; w < NW; w += 2){
      stepw(w, RWA, RaA, RaB);
      if (w + 1 < NW) stepw(w+1, RWB, RaB, RaA);
    }
  };

  // ---- epilogue: combine gate pre-acts, GRU nonlinearity, h update + limb stores ----
  auto epilogue = [&](const float* bih, const float* bhh, u16* hnl,
                      float2 &hp, bool cell2, bool init2,
                      const f32x4 &accI, const f32x4 &accH){
    #pragma unroll
    for (int i2 = 0; i2 < 4; i2++){
      int row = mh*16 + q4 + i2, col = jn*16 + mloc;
      if (g < 2) eg[g][row][col] = accI[i2] + accH[i2];
      else { eg[2][row][col] = accI[i2]; eg[3][row][col] = accH[i2]; }
    }
    __syncthreads();
    if (tid < 512){
      int bi = tid >> 4, nl2 = (tid & 15)*2, b = b0 + bi;
      float hv[2];
      float hpv0 = hp.x, hpv1 = hp.y;
      #pragma unroll
      for (int u = 0; u < 2; u++){
        int nl = nl2 + u, n = n0 + nl;
        float rr = 1.f/(1.f + expf(-(eg[0][bi][nl] + bih[n] + bhh[n])));
        float zz = 1.f/(1.f + expf(-(eg[1][bi][nl] + bih[512+n] + bhh[512+n])));
        float nn2 = tanhf(eg[2][bi][nl] + bih[1024+n] + rr*(eg[3][bi][nl] + bhh[1024+n]));
        float hprev = u ? hpv1 : hpv0;
        hv[u] = (1.f - zz)*nn2 + zz*hprev;
        if (cell2) h2loc[bi][nl] = hv[u];
      }
      hp.x = hv[0]; hp.y = hv[1];
      if (init2){ hp2.x = hv[0]; hp2.y = hv[1]; }
      u16 A0 = f2bf(hv[0]); float ra = hv[0] - bf2f(A0);
      u16 A1 = f2bf(ra);    float ra2 = ra - bf2f(A1);
      u16 A2 = f2bf(ra2);
      u16 B0 = f2bf(hv[1]); float rb = hv[1] - bf2f(B0);
      u16 B1 = f2bf(rb);    float rb2 = rb - bf2f(B1);
      u16 B2 = f2bf(rb2);
      size_t base = (size_t)b*512 + n0 + nl2;
      stu32((u32*)(hnl + base),          (u32)A0 | ((u32)B0 << 16));
      stu32((u32*)(hnl + 262144 + base), (u32)A1 | ((u32)B1 << 16));
      stu32((u32*)(hnl + 524288 + base), (u32)A2 | ((u32)B2 << 16));
    }
    __syncthreads();
    if (cell2){
      for (int e = tid; e < 288; e += 768){
        int c = e % 9, bi = e / 9;
        float s = 0.f;
        #pragma unroll
        for (int nl = 0; nl < 32; nl++) s += nfw[c*512 + n0 + nl]*h2loc[bi][nl];
        atomicAdd(&logacc[((size_t)t*512 + b0 + bi)*16 + c], s);
      }
    }
  };

  auto sample_phase = [&](int tp){
    for (int e = tid; e < 288; e += 768){
      int c = e % 9, bi = e / 9, b = b0 + bi;
      float lg = ldf(&logacc[((size_t)tp*512 + b)*16 + c]) + nfb[c];
      if (nstrip == 0) dout[((size_t)b*64 + tp)*9 + c] = lg;
      if (tp < 63){
        u32 ka, kb; step_key(tp, ka, kb);
        float rr = rng_uniform(ka, kb, (u32)(b*9 + c));
        float sg = 1.f/(1.f + expf(-lg));
        out_sh[bi][c] = (sg - rr > 0.f) ? (u16)0x3F80 : (u16)0;
      }
    }
    __syncthreads();
  };

  // ---- timestep loop ----
  for (t = 0; t < 64; t++){
    const u16* h1pl = hpl + (size_t)((t & 1) ? 1 : 0)*786432;
    u16*       h1nl = hpl + (size_t)((t & 1) ? 0 : 1)*786432;
    const u16* h2pl = hpl + (size_t)((t & 1) ? 2 : 3)*786432;
    u16*       h2nl = hpl + (size_t)((t & 1) ? 3 : 2)*786432;

    // GRU1: hh first (h1(t-1) already synced), then sample-gate, then ih
    f32x4 accI = {0,0,0,0}, accH = {0,0,0,0};
    run_phase(IC<1>{}, IC<8>{}, 512, (size_t)491520, h1pl, accH);
    if (t > 0){ waitbar(flgL, (u32)t); sample_phase(t-1); }
    run_phase(IC<0>{}, IC<5>{}, 320, (size_t)0, nullptr, accI);
    epilogue(bih1, bhh1, h1nl, hp1, false, (t == 0), accI, accH);
    arrive(flgH, (u32)(t+1));

    // GRU2: hh overlaps the h1 barrier; ih after it
    f32x4 accI2 = {0,0,0,0}, accH2 = {0,0,0,0};
    if (t == 0){
      waitbar(flgH, 1u);
      run_phase(IC<1>{}, IC<8>{}, 512, (size_t)2064384, h1nl, accH2);  // h2_prev == h1(0)
    } else {
      run_phase(IC<1>{}, IC<8>{}, 512, (size_t)2064384, h2pl, accH2);
      waitbar(flgH, (u32)(t+1));
    }
    run_phase(IC<1>{}, IC<8>{}, 512, (size_t)1277952, h1nl, accI2);
    epilogue(bih2, bhh2, h2nl, hp2, true, false, accI2, accH2);
    arrive(flgL, (u32)(t+1));
  }
  // tail: last logits row
  waitbar(flgL, 64u);
  sample_phase(63);
}

// ---------------- host ----------------
extern "C" void kernel_launch(void* const* d_in, const int* in_sizes, int n_in,
                              void* d_out, int out_size, void* d_ws, size_t ws_size,
                              hipStream_t stream) {
  (void)in_sizes; (void)n_in; (void)out_size; (void)ws_size;
  const float* z       = (const float*)d_in[0];
  const float* skel    = (const float*)d_in[2];
  const float* se      = (const float*)d_in[3];
  const float* ct1_w   = (const float*)d_in[6];
  const float* ct1_b   = (const float*)d_in[7];
  const float* bn1_g   = (const float*)d_in[8];
  const float* bn1_b   = (const float*)d_in[9];
  const float* bn1_m   = (const float*)d_in[10];
  const float* bn1_v   = (const float*)d_in[11];
  const float* ct2_w   = (const float*)d_in[12];
  const float* ct2_b   = (const float*)d_in[13];
  const float* bn2_g   = (const float*)d_in[14];
  const float* bn2_b   = (const float*)d_in[15];
  const float* bn2_m   = (const float*)d_in[16];
  const float* bn2_v   = (const float*)d_in[17];
  const float* hfc_w   = (const float*)d_in[18];
  const float* hfc_b   = (const float*)d_in[19];
  const float* g1_wih  = (const float*)d_in[20];
  const float* g1_whh  = (const float*)d_in[21];
  const float* g1_bih  = (const float*)d_in[22];
  const float* g1_bhh  = (const float*)d_in[23];
  const float* g2_wih  = (const float*)d_in[24];
  const float* g2_whh  = (const float*)d_in[25];
  const float* g2_bih  = (const float*)d_in[26];
  const float* g2_bhh  = (const float*)d_in[27];
  const float* nfc_w   = (const float*)d_in[28];
  const float* nfc_b   = (const float*)d_in[29];

  float* ws = (float*)d_ws;
  float* y1 = ws;                                  // conv intermediate (region reused by prep)
  u16* xh = (u16*)(ws + WOFF_XH);
  u16* xl = xh + 8388608;
  float* dout = (float*)d_out;

  k_conv1<<<dim3(L1, BATCH/8), 256, 0, stream>>>(z, ct1_w, ct1_b, bn1_g, bn1_b, bn1_m, bn1_v, y1);
  k_conv2<<<dim3(SLEN, BATCH/8), 256, 0, stream>>>(y1, ct2_w, ct2_b, bn2_g, bn2_b, bn2_m, bn2_v, xh, xl);
  k_prep<<<4096, 256, 0, stream>>>(g1_wih, g1_whh, g2_wih, g2_whh, skel, ws);
  k_h0<<<BATCH, 256, 0, stream>>>(se, hfc_w, hfc_b, ws);

  void* args[] = {
    (void*)&ws, (void*)&g1_bih, (void*)&g1_bhh, (void*)&g2_bih, (void*)&g2_bhh,
    (void*)&nfc_w, (void*)&nfc_b, (void*)&dout
  };
  hipLaunchCooperativeKernel((const void*)k_persist, dim3(256), dim3(768), args, 0, stream);
}

// Round 15
// 3607.968 us; speedup vs baseline: 2.0774x; 2.0774x over previous
//
#include <hip/hip_runtime.h>
#include <stdint.h>

typedef uint32_t u32; typedef uint16_t u16; typedef unsigned long long u64;
typedef __attribute__((ext_vector_type(8))) short short8;
typedef __attribute__((ext_vector_type(4))) float f32x4;

#define DEV static __device__ __forceinline__
#define MFMA16 __builtin_amdgcn_mfma_f32_16x16x32_bf16

#define BATCH 512
#define CD    64
#define ZL    16
#define HID   512
#define H2D   256
#define NC    9
#define SLEN  64
#define L1    35

#define JAX_PARTITIONABLE 1

// ---- workspace layout (f32-word offsets) ----
#define P_W      2850816   /* u16 per W limb plane-set */
#define WOFF_SKH 4276224   /* skel_hi u16 [64][512][16] */
#define WOFF_HPL 4538368   /* 4 states x 3 limbs x 262144 u16 */
#define WOFF_HF  6111232   /* h1_0 f32 262144 (state0 init) */
#define WOFF_LOG 7159808   /* f32 [64][512][16] */
#define WOFF_FLG 7684096   /* u32 flgH[256] + flgL[256] */
#define WOFF_XH  9175040   /* xin limb planes: 2 x 8,388,608 u16 */

template<int V> struct IC { static constexpr int value = V; };

DEV float bf2f(u16 h){ u32 u = ((u32)h) << 16; float f; __builtin_memcpy(&f,&u,4); return f; }
DEV u16 f2bf(float f){ u32 u; __builtin_memcpy(&u,&f,4); return (u16)((u + 0x7FFFu + ((u>>16)&1u)) >> 16); }

DEV float ldf(const float* p){ return __hip_atomic_load(p, __ATOMIC_RELAXED, __HIP_MEMORY_SCOPE_AGENT); }
DEV u32 ldu32(const u32* p){ return __hip_atomic_load(p, __ATOMIC_RELAXED, __HIP_MEMORY_SCOPE_AGENT); }
DEV u64 ldu64(const u64* p){ return __hip_atomic_load(p, __ATOMIC_RELAXED, __HIP_MEMORY_SCOPE_AGENT); }
DEV void stu32(u32* p, u32 v){ __hip_atomic_store(p, v, __ATOMIC_RELAXED, __HIP_MEMORY_SCOPE_AGENT); }

// ---------------- Threefry-2x32 ----------------
DEV void threefry2x32(u32 k0, u32 k1, u32 x0, u32 x1, u32 &o0, u32 &o1){
  const u32 ks2 = k0 ^ k1 ^ 0x1BD11BDAu;
#define TF_R(d) { x0 += x1; x1 = (x1 << (d)) | (x1 >> (32 - (d))); x1 ^= x0; }
  x0 += k0; x1 += k1;
  TF_R(13) TF_R(15) TF_R(26) TF_R(6)
  x0 += k1;  x1 += ks2 + 1u;
  TF_R(17) TF_R(29) TF_R(16) TF_R(24)
  x0 += ks2; x1 += k0 + 2u;
  TF_R(13) TF_R(15) TF_R(26) TF_R(6)
  x0 += k0;  x1 += k1 + 3u;
  TF_R(17) TF_R(29) TF_R(16) TF_R(24)
  x0 += k1;  x1 += ks2 + 4u;
  TF_R(13) TF_R(15) TF_R(26) TF_R(6)
  x0 += ks2; x1 += k0 + 5u;
#undef TF_R
  o0 = x0; o1 = x1;
}
DEV void step_key(int t, u32 &ka, u32 &kb){
#if JAX_PARTITIONABLE
  threefry2x32(0u, 42u, 0u, (u32)t, ka, kb);
#else
  u32 j0 = 2u*(u32)t, j1 = j0 + 1u, a0, a1;
  if (j0 < 64u){ threefry2x32(0u,42u, j0, 64u+j0, a0, a1); ka = a0; }
  else         { threefry2x32(0u,42u, j0-64u, j0, a0, a1); ka = a1; }
  if (j1 < 64u){ threefry2x32(0u,42u, j1, 64u+j1, a0, a1); kb = a0; }
  else         { threefry2x32(0u,42u, j1-64u, j1, a0, a1); kb = a1; }
#endif
}
DEV float rng_uniform(u32 ka, u32 kb, u32 f){
  u32 bits, o0, o1;
#if JAX_PARTITIONABLE
  threefry2x32(ka, kb, 0u, f, o0, o1);
  bits = o0 ^ o1;
#else
  const u32 HALF = (u32)(BATCH*NC/2);
  if (f < HALF){ threefry2x32(ka, kb, f, f+HALF, o0, o1); bits = o0; }
  else         { threefry2x32(ka, kb, f-HALF, f, o0, o1); bits = o1; }
#endif
  u32 fb = (bits >> 9) | 0x3F800000u;
  float fv; __builtin_memcpy(&fv,&fb,4);
  return fv - 1.0f;
}

// ---------------- ConvT1 ----------------
__global__ __launch_bounds__(256) void k_conv1(
    const float* __restrict__ z, const float* __restrict__ w1, const float* __restrict__ b1,
    const float* __restrict__ g1, const float* __restrict__ bt1, const float* __restrict__ m1,
    const float* __restrict__ v1, float* __restrict__ y1out)
{
  int t = blockIdx.x, bg = blockIdx.y*8, tid = threadIdx.x;
  __shared__ float zsh[2][8][CD];
  int k0 = t & 1, sA = (t-k0)>>1, sB = sA-1;
  bool vA = (sA>=0 && sA<ZL), vB = (sB>=0 && sB<ZL);
  for (int l = tid; l < 2*8*CD; l += 256){
    int p = l>>9, bb = (l>>6)&7, i = l&63;
    int s = p ? sB : sA; bool v = p ? vB : vA;
    zsh[p][bb][i] = v ? z[((bg+bb)*CD+i)*ZL + s] : 0.f;
  }
  __syncthreads();
  const float4* w1v = (const float4*)w1;
  for (int o = tid; o < HID; o += 256){
    float acc[8] = {0,0,0,0,0,0,0,0};
    for (int i = 0; i < CD; i++){
      float4 wv = w1v[i*HID + o];
      float wA = k0 ? wv.y : wv.x, wB = k0 ? wv.w : wv.z;
      #pragma unroll
      for (int bb = 0; bb < 8; bb++) acc[bb] += zsh[0][bb][i]*wA + zsh[1][bb][i]*wB;
    }
    float xb = b1[o], sc = g1[o]/sqrtf(v1[o]+1e-5f), mm = m1[o], be = bt1[o];
    #pragma unroll
    for (int bb = 0; bb < 8; bb++){
      float y = (acc[bb]+xb-mm)*sc + be;
      y = (y>0.f)? y : 0.2f*y;
      y1out[((bg+bb)*L1 + t)*HID + o] = y;
    }
  }
}

// ---------------- ConvT2 -> xin 2 limb planes [t][b][256] ----------------
__global__ __launch_bounds__(256) void k_conv2(
    const float* __restrict__ y1, const float* __restrict__ w2, const float* __restrict__ b2,
    const float* __restrict__ g2, const float* __restrict__ bt2, const float* __restrict__ m2,
    const float* __restrict__ v2, u16* __restrict__ xh, u16* __restrict__ xl)
{
  int t = blockIdx.x, bg = blockIdx.y*8, tid = threadIdx.x;
  __shared__ float ysh[2][8][HID];
  int k0 = t & 1, sA = (t-k0)>>1, sB = sA-1;
  bool vB = (sB >= 0);
  for (int l = tid; l < 2*8*HID; l += 256){
    int p = l>>12, bb = (l>>9)&7, o = l&511;
    int s = p ? sB : sA; bool v = p ? vB : true;
    ysh[p][bb][o] = v ? y1[((bg+bb)*L1 + s)*HID + o] : 0.f;
  }
  __syncthreads();
  int c = tid;
  float acc[8] = {0,0,0,0,0,0,0,0};
  const float4* w2v = (const float4*)w2;
  for (int o4 = 0; o4 < HID; o4 += 4){
    float wA[4], wB[4];
    #pragma unroll
    for (int j = 0; j < 4; j++){
      float4 wv = w2v[(o4+j)*H2D + c];
      wA[j] = k0 ? wv.y : wv.x; wB[j] = k0 ? wv.w : wv.z;
    }
    #pragma unroll
    for (int bb = 0; bb < 8; bb++){
      const float4 ya = *(const float4*)&ysh[0][bb][o4];
      const float4 yb = *(const float4*)&ysh[1][bb][o4];
      acc[bb] += ya.x*wA[0]+ya.y*wA[1]+ya.z*wA[2]+ya.w*wA[3]
               + yb.x*wB[0]+yb.y*wB[1]+yb.z*wB[2]+yb.w*wB[3];
    }
  }
  float xb = b2[c], sc = g2[c]/sqrtf(v2[c]+1e-5f), mm = m2[c], be = bt2[c];
  #pragma unroll
  for (int bb = 0; bb < 8; bb++){
    float y = (acc[bb]+xb-mm)*sc + be;
    y = (y>0.f)? y : 0.2f*y;
    u16 hi = f2bf(y); u16 lo = f2bf(y - bf2f(hi));
    size_t o = ((size_t)t*512 + bg + bb)*256 + c;
    xh[o] = hi; xl[o] = lo;
  }
}

// ---------------- prep: W 3-limb k-major planes, skel_hi, zero logacc+flags ------
// cat K-layout PERMUTED to [xin 256 | skel 9 | out 9 | pad] (wih1 cols permuted).
__global__ __launch_bounds__(256) void k_prep(
    const float* __restrict__ wih1, const float* __restrict__ whh1,
    const float* __restrict__ wih2, const float* __restrict__ whh2,
    const float* __restrict__ skel, float* __restrict__ ws)
{
  u16* wp = (u16*)ws;
  u16* skh = (u16*)(ws + WOFF_SKH);
  float* logacc = ws + WOFF_LOG;
  u32* flg = (u32*)(ws + WOFF_FLG);
  int stride = gridDim.x*256, i0 = blockIdx.x*256 + threadIdx.x;
  for (int i = i0; i < P_W; i += stride){
    int r = i; float v;
    if (r < 491520){
      int n = r/320, k = r - n*320; v = 0.f;
      if (k < 256)      v = wih1[(size_t)n*274 + 9 + k];          // xin
      else if (k < 265) v = wih1[(size_t)n*274 + 265 + (k-256)];  // skel
      else if (k < 274) v = wih1[(size_t)n*274 + (k-265)];        // out
    }
    else if (r < 1277952){ int rr = r-491520;  int n = rr>>9, k = rr&511; v = whh1[((size_t)n<<9)+k]; }
    else if (r < 2064384){ int rr = r-1277952; int n = rr>>9, k = rr&511; v = wih2[((size_t)n<<9)+k]; }
    else                 { int rr = r-2064384; int n = rr>>9, k = rr&511; v = whh2[((size_t)n<<9)+k]; }
    u16 l0 = f2bf(v);
    float r1 = v - bf2f(l0); u16 l1 = f2bf(r1);
    float r2 = r1 - bf2f(l1); u16 l2 = f2bf(r2);
    wp[i] = l0; wp[P_W + i] = l1; wp[2*P_W + i] = l2;
  }
  for (int i = i0; i < 524288; i += stride){
    int c = i & 15, r = i >> 4, b = r & 511, tt = r >> 9;
    float v = (c < 9) ? skel[((size_t)b*64 + tt)*9 + c] : 0.f;
    skh[i] = f2bf(v);
  }
  for (int i = i0; i < 524288; i += stride) logacc[i] = 0.f;
  for (int i = i0; i < 512; i += stride) flg[i] = 0u;
}

// ---------------- h0: h1a f32 + 3 limb planes (state 0) ----------------
__global__ __launch_bounds__(256) void k_h0(
    const float* __restrict__ se, const float* __restrict__ w, const float* __restrict__ bias,
    float* __restrict__ ws)
{
  float* h1af = ws + WOFF_HF;
  u16* hpl = (u16*)(ws + WOFF_HPL);
  int b = blockIdx.x, tid = threadIdx.x;
  __shared__ float ssh[HID];
  for (int i = tid; i < HID; i += 256) ssh[i] = se[b*HID + i];
  __syncthreads();
  for (int j = tid; j < HID; j += 256){
    float acc = 0.f;
    for (int q = 0; q < HID; q++) acc += ssh[q]*w[j*HID + q];
    float v = acc + bias[j];
    h1af[(size_t)b*512 + j] = v;
    u16 l0 = f2bf(v);
    float r1 = v - bf2f(l0); u16 l1 = f2bf(r1);
    float r2 = r1 - bf2f(l1); u16 l2 = f2bf(r2);
    hpl[(size_t)b*512 + j] = l0;
    hpl[262144 + (size_t)b*512 + j] = l1;
    hpl[524288 + (size_t)b*512 + j] = l2;
  }
}

// ---------------- persistent MFMA recurrence (3-limb bf16 split-6) ----------------
// SESSION-BEST configuration (verified r11/r13: steady ~3085us, dur ~3.61ms):
// r6 structure + XCD-aware bid decode. xcd = bid&7 hosts nstrips {2*xcd,2*xcd+1}
// -> 16 same-nstrip WGs per XCD read IDENTICAL W strips => W L2-resident.
// W MUST be staged via coalesced cooperative loads -> LDS (direct per-wave W
// gathers miss cache: proven 4x in r2/r3/r5/r14). h-state on sc1 agent atomics
// (fences invalidate L2: r10). 768 thr = 12 waves = (gate g, m-half, n-half);
// 16x16x32 MFMA; W+A reg-staged ->LDS (pitch 72), depth-2 prefetch; soft_bar
// waits lgkmcnt ONLY so global prefetches stay in flight across barriers.
__global__ __launch_bounds__(768, 1) void k_persist(
    float* __restrict__ ws,
    const float* __restrict__ bih1, const float* __restrict__ bhh1,
    const float* __restrict__ bih2, const float* __restrict__ bhh2,
    const float* __restrict__ nfw,  const float* __restrict__ nfb,
    float* __restrict__ dout)
{
  const int tid = threadIdx.x;
  const int wvid = __builtin_amdgcn_readfirstlane(tid >> 6);
  const int g  = wvid >> 2;           // gate 0..2
  const int mh = (wvid >> 1) & 1;     // m-half
  const int jn = wvid & 1;            // n-half
  const int lane = tid & 63;
  const int mloc = lane & 15;
  const int q8 = (lane >> 4) * 8;
  const int q4 = (lane >> 4) * 4;
  // XCD-aware decode (bijective): xcd = bid&7 -> nstrips {2*xcd, 2*xcd+1}
  const int bid = blockIdx.x;
  const int xcd = bid & 7;
  const int rr2 = bid >> 3;                    // 0..31
  const int bg = rr2 >> 1;                     // 0..15
  const int nstrip = (xcd << 1) | (rr2 & 1);   // 0..15
  const int b0 = bg * 32;
  const int n0 = nstrip * 32;

  u16* wp = (u16*)ws;
  const u16* skh = (const u16*)(ws + WOFF_SKH);
  u16* hpl = (u16*)(ws + WOFF_HPL);
  const float* h1af = ws + WOFF_HF;
  float* logacc = ws + WOFF_LOG;
  u32* flgH = (u32*)(ws + WOFF_FLG);
  u32* flgL = flgH + 256;
  const u16* xh = (const u16*)(ws + WOFF_XH);
  const u16* xl = xh + 8388608;

  __shared__ __align__(16) u16 Abuf[2][3][32][72];     // 27,648 B
  __shared__ __align__(16) u16 Wbuf[2][3][3][32][72];  // 82,944 B
  __shared__ __align__(16) float eg[4][32][33];        // 16,896 B
  __shared__ __align__(16) float h2loc[32][33];        //  4,224 B
  __shared__ __align__(16) u16 out_sh[32][12];         //    768 B

  int t = 0;
  float2 hp1 = {0.f,0.f}, hp2 = {0.f,0.f};

  // prologue: zero out_sh, load own h1_0 tile into regs (tid<512)
  if (tid < 384) ((u16*)out_sh)[tid] = 0;
  if (tid < 512){
    int bi = tid >> 4, nl2 = (tid & 15)*2;
    hp1.x = h1af[(size_t)(b0+bi)*512 + n0 + nl2];
    hp1.y = h1af[(size_t)(b0+bi)*512 + n0 + nl2 + 1];
  }

  auto soft_bar = [&](){
    __builtin_amdgcn_sched_barrier(0);
    asm volatile("s_waitcnt lgkmcnt(0)" ::: "memory");
    __builtin_amdgcn_s_barrier();
    __builtin_amdgcn_sched_barrier(0);
  };
  auto arrive = [&](u32* f, u32 tok){
    __syncthreads();
    if (tid == 0) __hip_atomic_store(&f[bg*16 + nstrip], tok, __ATOMIC_RELEASE, __HIP_MEMORY_SCOPE_AGENT);
  };
  auto waitbar = [&](u32* f, u32 tok){
    if (tid < 16) while (ldu32(&f[bg*16 + tid]) < tok) __builtin_amdgcn_s_sleep(2);
    __syncthreads();
  };

  // ---- one GRU mat-pair phase: acc += A(K) * W^T strip, K in 64-wide windows ----
  auto run_phase = [&](auto mc, auto nwc, int Kp, size_t SUB, const u16* hb, f32x4 &acc){
    constexpr int MODE = decltype(mc)::value;   // 0 = cat (2 A-limbs), 1 = h-state (3)
    constexpr int NW = decltype(nwc)::value;
    short8 RwA[3], RwB[3];
    u64 RaA[2], RaB[2];

    auto loadW = [&](short8 (&R)[3], int kc){
      #pragma unroll
      for (int i = 0; i < 3; i++){
        int idx = tid + i*768;                 // 0..2303
        int gp = idx >> 8, r = idx & 255, nn = r >> 3, ck = r & 7;
        const u16* src = wp + (size_t)(gp % 3)*P_W + SUB
                       + ((size_t)((gp/3)*512 + n0 + nn))*(size_t)Kp + kc + ck*8;
        R[i] = *(const short8*)src;
      }
    };
    auto writeW = [&](int buf, short8 (&R)[3]){
      #pragma unroll
      for (int i = 0; i < 3; i++){
        int idx = tid + i*768;
        int gp = idx >> 8, r = idx & 255, nn = r >> 3, ck = r & 7;
        *(short8*)&Wbuf[buf][gp/3][gp%3][nn][ck*8] = R[i];
      }
    };
    auto loadA = [&](u64 (&R)[2], int kc){
      int idx = tid;
      if constexpr (MODE == 1){
        int p = idx >> 8, r = idx & 255, bi = r >> 3, ck = r & 7;
        const u16* src = hb + (size_t)p*262144 + (size_t)(b0+bi)*512 + kc + ck*8;
        R[0] = ldu64((const u64*)src);
        R[1] = ldu64((const u64*)(src + 4));
      } else {
        if (idx < 512){
          int p = idx >> 8, r = idx & 255, bi = r >> 3, ck = r & 7;
          if (kc < 256){
            const u64* src = (const u64*)((p ? xl : xh) + ((size_t)t*512 + b0 + bi)*256 + kc + ck*8);
            R[0] = src[0]; R[1] = src[1];
          } else {
            u64 w0 = 0, w1 = 0;
            if (p == 0){
              #pragma unroll
              for (int e2 = 0; e2 < 4; e2++){
                int kg = 256 + ck*8 + e2;
                u16 val = 0;
                if (kg < 265) val = skh[((size_t)t*512 + b0 + bi)*16 + (kg - 256)];
                else if (kg < 274) val = out_sh[bi][kg - 265];
                w0 |= ((u64)val) << (16*e2);
              }
              #pragma unroll
              for (int e2 = 0; e2 < 4; e2++){
                int kg = 260 + ck*8 + e2;
                u16 val = 0;
                if (kg < 265) val = skh[((size_t)t*512 + b0 + bi)*16 + (kg - 256)];
                else if (kg < 274) val = out_sh[bi][kg - 265];
                w1 |= ((u64)val) << (16*e2);
              }
            }
            R[0] = w0; R[1] = w1;
          }
        }
      }
    };
    auto writeA = [&](int buf, u64 (&R)[2]){
      constexpr int NCH = (MODE == 1) ? 768 : 512;
      int idx = tid;
      if (idx < NCH){
        int p = idx >> 8, r = idx & 255, bi = r >> 3, ck = r & 7;
        u64* d = (u64*)&Abuf[buf][p][bi][ck*8];
        d[0] = R[0]; d[1] = R[1];
      }
    };
    auto compute = [&](int buf){
      const int ar = mh*16 + mloc;
      const int wr = jn*16 + mloc;
      #pragma unroll
      for (int ks = 0; ks < 2; ks++){
        const int ko = ks*32 + q8;
        short8 a0 = *(const short8*)&Abuf[buf][0][ar][ko];
        short8 a1 = *(const short8*)&Abuf[buf][1][ar][ko];
        short8 a2 = {};
        if constexpr (MODE == 1) a2 = *(const short8*)&Abuf[buf][2][ar][ko];
        short8 w0 = *(const short8*)&Wbuf[buf][g][0][wr][ko];
        short8 w1 = *(const short8*)&Wbuf[buf][g][1][wr][ko];
        short8 w2 = *(const short8*)&Wbuf[buf][g][2][wr][ko];
        acc = MFMA16(a0, w0, acc, 0, 0, 0);
        acc = MFMA16(a0, w1, acc, 0, 0, 0);
        acc = MFMA16(a1, w0, acc, 0, 0, 0);
        acc = MFMA16(a0, w2, acc, 0, 0, 0);
        if constexpr (MODE == 1) acc = MFMA16(a2, w0, acc, 0, 0, 0);
        acc = MFMA16(a1, w1, acc, 0, 0, 0);
      }
    };

    // prologue: windows 0,1 issued; window 0 written
    loadW(RwA, 0); loadA(RaA, 0);
    loadW(RwB, 64); loadA(RaB, 64);
    writeW(0, RwA); writeA(0, RaA);
    soft_bar();

    auto stepw = [&](int w, short8 (&Rl)[3], u64 (&Al)[2], short8 (&Rs)[3], u64 (&As)[2]){
      if (w + 2 < NW){ loadW(Rl, (w+2)*64); loadA(Al, (w+2)*64); }   // in flight across barriers
      compute(w & 1);
      if (w + 1 < NW){ writeW((w+1)&1, Rs); writeA((w+1)&1, As); }   // value-dep vmcnt only
      soft_bar();
    };
    #pragma unroll
    for (int w = 0; w < NW; w += 2){
      stepw(w, RwA, RaA, RwB, RaB);
      if (w + 1 < NW) stepw(w+1, RwB, RaB, RwA, RaA);
    }
  };

  // ---- epilogue: combine gate pre-acts, GRU nonlinearity, h update + limb stores ----
  auto epilogue = [&](const float* bih, const float* bhh, u16* hnl,
                      float2 &hp, bool cell2, bool init2,
                      const f32x4 &accI, const f32x4 &accH){
    #pragma unroll
    for (int i2 = 0; i2 < 4; i2++){
      int row = mh*16 + q4 + i2, col = jn*16 + mloc;
      if (g < 2) eg[g][row][col] = accI[i2] + accH[i2];
      else { eg[2][row][col] = accI[i2]; eg[3][row][col] = accH[i2]; }
    }
    __syncthreads();
    if (tid < 512){
      int bi = tid >> 4, nl2 = (tid & 15)*2, b = b0 + bi;
      float hv[2];
      float hpv0 = hp.x, hpv1 = hp.y;
      #pragma unroll
      for (int u = 0; u < 2; u++){
        int nl = nl2 + u, n = n0 + nl;
        float rr = 1.f/(1.f + expf(-(eg[0][bi][nl] + bih[n] + bhh[n])));
        float zz = 1.f/(1.f + expf(-(eg[1][bi][nl] + bih[512+n] + bhh[512+n])));
        float nn2 = tanhf(eg[2][bi][nl] + bih[1024+n] + rr*(eg[3][bi][nl] + bhh[1024+n]));
        float hprev = u ? hpv1 : hpv0;
        hv[u] = (1.f - zz)*nn2 + zz*hprev;
        if (cell2) h2loc[bi][nl] = hv[u];
      }
      hp.x = hv[0]; hp.y = hv[1];
      if (init2){ hp2.x = hv[0]; hp2.y = hv[1]; }
      u16 A0 = f2bf(hv[0]); float ra = hv[0] - bf2f(A0);
      u16 A1 = f2bf(ra);    float ra2 = ra - bf2f(A1);
      u16 A2 = f2bf(ra2);
      u16 B0 = f2bf(hv[1]); float rb = hv[1] - bf2f(B0);
      u16 B1 = f2bf(rb);    float rb2 = rb - bf2f(B1);
      u16 B2 = f2bf(rb2);
      size_t base = (size_t)b*512 + n0 + nl2;
      stu32((u32*)(hnl + base),          (u32)A0 | ((u32)B0 << 16));
      stu32((u32*)(hnl + 262144 + base), (u32)A1 | ((u32)B1 << 16));
      stu32((u32*)(hnl + 524288 + base), (u32)A2 | ((u32)B2 << 16));
    }
    __syncthreads();
    if (cell2){
      for (int e = tid; e < 288; e += 768){
        int c = e % 9, bi = e / 9;
        float s = 0.f;
        #pragma unroll
        for (int nl = 0; nl < 32; nl++) s += nfw[c*512 + n0 + nl]*h2loc[bi][nl];
        atomicAdd(&logacc[((size_t)t*512 + b0 + bi)*16 + c], s);
      }
    }
  };

  auto sample_phase = [&](int tp){
    for (int e = tid; e < 288; e += 768){
      int c = e % 9, bi = e / 9, b = b0 + bi;
      float lg = ldf(&logacc[((size_t)tp*512 + b)*16 + c]) + nfb[c];
      if (nstrip == 0) dout[((size_t)b*64 + tp)*9 + c] = lg;
      if (tp < 63){
        u32 ka, kb; step_key(tp, ka, kb);
        float rr = rng_uniform(ka, kb, (u32)(b*9 + c));
        float sg = 1.f/(1.f + expf(-lg));
        out_sh[bi][c] = (sg - rr > 0.f) ? (u16)0x3F80 : (u16)0;
      }
    }
    __syncthreads();
  };

  // ---- timestep loop ----
  for (t = 0; t < 64; t++){
    const u16* h1pl = hpl + (size_t)((t & 1) ? 1 : 0)*786432;
    u16*       h1nl = hpl + (size_t)((t & 1) ? 0 : 1)*786432;
    const u16* h2pl = hpl + (size_t)((t & 1) ? 2 : 3)*786432;
    u16*       h2nl = hpl + (size_t)((t & 1) ? 3 : 2)*786432;

    // GRU1: hh first (h1(t-1) already synced), then sample-gate, then ih
    f32x4 accI = {0,0,0,0}, accH = {0,0,0,0};
    run_phase(IC<1>{}, IC<8>{}, 512, (size_t)491520, h1pl, accH);
    if (t > 0){ waitbar(flgL, (u32)t); sample_phase(t-1); }
    run_phase(IC<0>{}, IC<5>{}, 320, (size_t)0, nullptr, accI);
    epilogue(bih1, bhh1, h1nl, hp1, false, (t == 0), accI, accH);
    arrive(flgH, (u32)(t+1));

    // GRU2: hh overlaps the h1 barrier; ih after it
    f32x4 accI2 = {0,0,0,0}, accH2 = {0,0,0,0};
    if (t == 0){
      waitbar(flgH, 1u);
      run_phase(IC<1>{}, IC<8>{}, 512, (size_t)2064384, h1nl, accH2);  // h2_prev == h1(0)
    } else {
      run_phase(IC<1>{}, IC<8>{}, 512, (size_t)2064384, h2pl, accH2);
      waitbar(flgH, (u32)(t+1));
    }
    run_phase(IC<1>{}, IC<8>{}, 512, (size_t)1277952, h1nl, accI2);
    epilogue(bih2, bhh2, h2nl, hp2, true, false, accI2, accH2);
    arrive(flgL, (u32)(t+1));
  }
  // tail: last logits row
  waitbar(flgL, 64u);
  sample_phase(63);
}

// ---------------- host ----------------
extern "C" void kernel_launch(void* const* d_in, const int* in_sizes, int n_in,
                              void* d_out, int out_size, void* d_ws, size_t ws_size,
                              hipStream_t stream) {
  (void)in_sizes; (void)n_in; (void)out_size; (void)ws_size;
  const float* z       = (const float*)d_in[0];
  const float* skel    = (const float*)d_in[2];
  const float* se      = (const float*)d_in[3];
  const float* ct1_w   = (const float*)d_in[6];
  const float* ct1_b   = (const float*)d_in[7];
  const float* bn1_g   = (const float*)d_in[8];
  const float* bn1_b   = (const float*)d_in[9];
  const float* bn1_m   = (const float*)d_in[10];
  const float* bn1_v   = (const float*)d_in[11];
  const float* ct2_w   = (const float*)d_in[12];
  const float* ct2_b   = (const float*)d_in[13];
  const float* bn2_g   = (const float*)d_in[14];
  const float* bn2_b   = (const float*)d_in[15];
  const float* bn2_m   = (const float*)d_in[16];
  const float* bn2_v   = (const float*)d_in[17];
  const float* hfc_w   = (const float*)d_in[18];
  const float* hfc_b   = (const float*)d_in[19];
  const float* g1_wih  = (const float*)d_in[20];
  const float* g1_whh  = (const float*)d_in[21];
  const float* g1_bih  = (const float*)d_in[22];
  const float* g1_bhh  = (const float*)d_in[23];
  const float* g2_wih  = (const float*)d_in[24];
  const float* g2_whh  = (const float*)d_in[25];
  const float* g2_bih  = (const float*)d_in[26];
  const float* g2_bhh  = (const float*)d_in[27];
  const float* nfc_w   = (const float*)d_in[28];
  const float* nfc_b   = (const float*)d_in[29];

  float* ws = (float*)d_ws;
  float* y1 = ws;                                  // conv intermediate (region reused by prep)
  u16* xh = (u16*)(ws + WOFF_XH);
  u16* xl = xh + 8388608;
  float* dout = (float*)d_out;

  k_conv1<<<dim3(L1, BATCH/8), 256, 0, stream>>>(z, ct1_w, ct1_b, bn1_g, bn1_b, bn1_m, bn1_v, y1);
  k_conv2<<<dim3(SLEN, BATCH/8), 256, 0, stream>>>(y1, ct2_w, ct2_b, bn2_g, bn2_b, bn2_m, bn2_v, xh, xl);
  k_prep<<<4096, 256, 0, stream>>>(g1_wih, g1_whh, g2_wih, g2_whh, skel, ws);
  k_h0<<<BATCH, 256, 0, stream>>>(se, hfc_w, hfc_b, ws);

  void* args[] = {
    (void*)&ws, (void*)&g1_bih, (void*)&g1_bhh, (void*)&g2_bih, (void*)&g2_bhh,
    (void*)&nfc_w, (void*)&nfc_b, (void*)&dout
  };
  hipLaunchCooperativeKernel((const void*)k_persist, dim3(256), dim3(768), args, 0, stream);
}